// Round 1
// baseline (1095.127 us; speedup 1.0000x reference)
//
#include <hip/hip_runtime.h>
#include <hip/hip_bf16.h>
#include <math.h>

#define DEV_INLINE __device__ __forceinline__

constexpr int B_    = 4;
constexpr int QLEN  = 512;
constexpr int KLEN  = 1024;
constexpr int DIM   = 512;
constexpr int H_MA  = 4;
constexpr int H_CA  = 2;
constexpr int CHUNK = 4;
constexpr float EPS = 1e-6f;
constexpr float INV_SCALE = 1.0f / 22.62741699796952f;  // 1/sqrt(512)

// ---------------------------------------------------------------------------
// Generic 64x64 fp32 GEMM tiles (BK=16, 256 threads, 4x4 per thread)
// ---------------------------------------------------------------------------

// C[bm..bm+64, bn..bn+64] = A[M,K] @ B[K,N] (+bias), all row-major.
DEV_INLINE void gemm_nn_tile(const float* __restrict__ A, int lda,
                             const float* __restrict__ Bm, int ldb,
                             float* __restrict__ C, int ldc,
                             int K, const float* __restrict__ bias,
                             int bm, int bn)
{
    __shared__ float As[16][68];
    __shared__ float Bs[16][68];
    const int tid  = threadIdx.x;
    const int tm   = (tid >> 4) << 2;   // 0..60
    const int tn   = (tid & 15) << 2;   // 0..60
    const int arow = tid >> 2;          // 0..63
    const int acol = (tid & 3) << 2;    // 0,4,8,12
    const int brow = tid >> 4;          // 0..15
    const int bcol = (tid & 15) << 2;   // 0..60
    float acc[4][4] = {};

    for (int k0 = 0; k0 < K; k0 += 16) {
        const float4 av = *(const float4*)(A + (size_t)(bm + arow) * lda + k0 + acol);
        const float4 bv = *(const float4*)(Bm + (size_t)(k0 + brow) * ldb + bn + bcol);
        __syncthreads();
        As[acol + 0][arow] = av.x;
        As[acol + 1][arow] = av.y;
        As[acol + 2][arow] = av.z;
        As[acol + 3][arow] = av.w;
        *(float4*)(&Bs[brow][bcol]) = bv;
        __syncthreads();
#pragma unroll
        for (int kk = 0; kk < 16; ++kk) {
            const float4 a = *(const float4*)&As[kk][tm];
            const float4 b = *(const float4*)&Bs[kk][tn];
            const float ar[4] = {a.x, a.y, a.z, a.w};
            const float br[4] = {b.x, b.y, b.z, b.w};
#pragma unroll
            for (int i = 0; i < 4; ++i)
#pragma unroll
                for (int j = 0; j < 4; ++j)
                    acc[i][j] = fmaf(ar[i], br[j], acc[i][j]);
        }
    }
#pragma unroll
    for (int i = 0; i < 4; ++i) {
        float4 o;
        float* op = (float*)&o;
#pragma unroll
        for (int j = 0; j < 4; ++j)
            op[j] = acc[i][j] + (bias ? bias[bn + tn + j] : 0.0f);
        *(float4*)(C + (size_t)(bm + tm + i) * ldc + bn + tn) = o;
    }
}

// C[bm.., bn..] = A[M,K] @ B[N,K]^T * scale + addv  (both operands k-inner)
DEV_INLINE void gemm_nt_tile(const float* __restrict__ A, int lda,
                             const float* __restrict__ Bm, int ldb,
                             float* __restrict__ C, int ldc,
                             int K, float scale, float addv,
                             int bm, int bn)
{
    __shared__ float As[16][68];
    __shared__ float Bs[16][68];
    const int tid = threadIdx.x;
    const int tm  = (tid >> 4) << 2;
    const int tn  = (tid & 15) << 2;
    const int row = tid >> 2;          // 0..63
    const int col = (tid & 3) << 2;    // 0,4,8,12
    float acc[4][4] = {};

    for (int k0 = 0; k0 < K; k0 += 16) {
        const float4 av = *(const float4*)(A + (size_t)(bm + row) * lda + k0 + col);
        const float4 bv = *(const float4*)(Bm + (size_t)(bn + row) * ldb + k0 + col);
        __syncthreads();
        As[col + 0][row] = av.x;
        As[col + 1][row] = av.y;
        As[col + 2][row] = av.z;
        As[col + 3][row] = av.w;
        Bs[col + 0][row] = bv.x;
        Bs[col + 1][row] = bv.y;
        Bs[col + 2][row] = bv.z;
        Bs[col + 3][row] = bv.w;
        __syncthreads();
#pragma unroll
        for (int kk = 0; kk < 16; ++kk) {
            const float4 a = *(const float4*)&As[kk][tm];
            const float4 b = *(const float4*)&Bs[kk][tn];
            const float ar[4] = {a.x, a.y, a.z, a.w};
            const float br[4] = {b.x, b.y, b.z, b.w};
#pragma unroll
            for (int i = 0; i < 4; ++i)
#pragma unroll
                for (int j = 0; j < 4; ++j)
                    acc[i][j] = fmaf(ar[i], br[j], acc[i][j]);
        }
    }
#pragma unroll
    for (int i = 0; i < 4; ++i) {
        float4 o;
        float* op = (float*)&o;
#pragma unroll
        for (int j = 0; j < 4; ++j)
            op[j] = acc[i][j] * scale + addv;
        *(float4*)(C + (size_t)(bm + tm + i) * ldc + bn + tn) = o;
    }
}

// ---------------------------------------------------------------------------
// Kernels
// ---------------------------------------------------------------------------

__global__ __launch_bounds__(256) void gemm_nn_kernel(
    const float* __restrict__ A, int lda,
    const float* __restrict__ Bm, int ldb,
    float* __restrict__ C, int ldc,
    int K, const float* __restrict__ bias)
{
    gemm_nn_tile(A, lda, Bm, ldb, C, ldc, K, bias, blockIdx.x * 64, blockIdx.y * 64);
}

// e[z, q, k] = (QP[b,q,h*HD:+HD] . KP[b,k,h*HD:+HD]) / SCALE + (radd ? radd[0] : 0)
__global__ __launch_bounds__(256) void energy_nt_kernel(
    const float* __restrict__ QP, const float* __restrict__ KP,
    float* __restrict__ E, int H, int HD, const float* __restrict__ radd)
{
    const int z = blockIdx.z;
    const int b = z / H;
    const int h = z - b * H;
    const float* A  = QP + (size_t)b * QLEN * DIM + h * HD;
    const float* Bm = KP + (size_t)b * KLEN * DIM + h * HD;
    float* C = E + (size_t)z * QLEN * KLEN;
    const float addv = radd ? radd[0] : 0.0f;
    gemm_nt_tile(A, DIM, Bm, DIM, C, KLEN, HD, INV_SCALE, addv,
                 blockIdx.x * 64, blockIdx.y * 64);
}

// in-place: PCP holds e_ma rows on input; writes pcp = p*cp and icp = 1/max(cp,EPS)
__global__ __launch_bounds__(256) void ma_row_kernel(float* __restrict__ PCP,
                                                     float* __restrict__ ICP)
{
    const size_t row = blockIdx.x;
    float* pe = PCP + row * KLEN;
    float* pi = ICP + row * KLEN;
    const int tid = threadIdx.x;
    const int lane = tid & 63, wid = tid >> 6;

    const float4 ev = *(const float4*)(pe + tid * 4);
    float e[4] = {ev.x, ev.y, ev.z, ev.w};
    float p[4], l[4], s[4];
    float run = 0.0f;
#pragma unroll
    for (int j = 0; j < 4; ++j) {
        p[j] = 1.0f / (1.0f + expf(-e[j]));
        float om = 1.0f - p[j];
        om = fminf(fmaxf(om, EPS), 1.0f);
        l[j] = logf(om);
        run += l[j];
        s[j] = run;
    }
    const float t = run;
    float v = t;
#pragma unroll
    for (int off = 1; off < 64; off <<= 1) {
        const float u = __shfl_up(v, off);
        if (lane >= off) v += u;
    }
    __shared__ float wsum[4];
    if (lane == 63) wsum[wid] = v;
    __syncthreads();
    float base = v - t;
    for (int w = 0; w < wid; ++w) base += wsum[w];

    float4 po, io;
    float* pp = (float*)&po;
    float* ip = (float*)&io;
#pragma unroll
    for (int j = 0; j < 4; ++j) {
        const float cum = base + s[j];               // inclusive cumsum of log1mp
        const float cp  = expf(cum - l[j]);          // exclusive cumprod
        pp[j] = p[j] * cp;
        ip[j] = 1.0f / fmaxf(cp, EPS);
    }
    *(float4*)(pe + tid * 4) = po;
    *(float4*)(pi + tid * 4) = io;
}

// in-place: SE holds e_ca rows on input; writes se and denom (moving sum back=3)
__global__ __launch_bounds__(256) void ca_row_kernel(float* __restrict__ SE,
                                                     float* __restrict__ DEN)
{
    const size_t row = blockIdx.x;
    float* ps = SE + row * KLEN;
    float* pd = DEN + row * KLEN;
    const int tid = threadIdx.x;
    const int lane = tid & 63, wid = tid >> 6;

    const float4 ev = *(const float4*)(ps + tid * 4);
    float e[4] = {ev.x, ev.y, ev.z, ev.w};
    float m = fmaxf(fmaxf(e[0], e[1]), fmaxf(e[2], e[3]));
#pragma unroll
    for (int off = 32; off >= 1; off >>= 1)
        m = fmaxf(m, __shfl_xor(m, off));
    __shared__ float wmax[4];
    if (lane == 0) wmax[wid] = m;
    __syncthreads();
    m = fmaxf(fmaxf(wmax[0], wmax[1]), fmaxf(wmax[2], wmax[3]));

    __shared__ float sh[KLEN + 3];   // sh[3+k] = se[k], sh[0..2] = 0
    if (tid < 3) sh[tid] = 0.0f;
    float se[4];
#pragma unroll
    for (int j = 0; j < 4; ++j) {
        se[j] = fmaxf(expf(e[j] - m), 1e-5f);
        sh[3 + tid * 4 + j] = se[j];
    }
    __syncthreads();
    float4 so, do_;
    float* sp = (float*)&so;
    float* dp = (float*)&do_;
#pragma unroll
    for (int j = 0; j < 4; ++j) {
        const int k = tid * 4 + j;
        sp[j] = se[j];
        dp[j] = sh[3 + k] + sh[2 + k] + sh[1 + k] + sh[k];
    }
    *(float4*)(ps + tid * 4) = so;
    *(float4*)(pd + tid * 4) = do_;
}

// alpha recurrence; ALPHA buffer initially holds pcp rows, overwritten with alpha.
__global__ __launch_bounds__(1024) void alpha_kernel(float* __restrict__ PCP,
                                                     const float* __restrict__ ICP)
{
    const int z = blockIdx.x;                 // (b, h_ma)
    float* base = PCP + (size_t)z * QLEN * KLEN;
    const float* ibase = ICP + (size_t)z * QLEN * KLEN;
    const int k = threadIdx.x;
    const int lane = k & 63, wid = k >> 6;
    __shared__ float wpart[16];

    float aw = (k == 0) ? 1.0f : 0.0f;
    float pcp_c = base[k];
    float icp_c = ibase[k];

    for (int q = 0; q < QLEN; ++q) {
        float pcp_n = 0.0f, icp_n = 0.0f;
        if (q + 1 < QLEN) {                    // prefetch next row (overlaps scan)
            pcp_n = base[(size_t)(q + 1) * KLEN + k];
            icp_n = ibase[(size_t)(q + 1) * KLEN + k];
        }
        const float t = aw * icp_c;
        float v = t;
#pragma unroll
        for (int off = 1; off < 64; off <<= 1) {
            const float u = __shfl_up(v, off);
            if (lane >= off) v += u;
        }
        if (lane == 63) wpart[wid] = v;
        __syncthreads();
        float pre = 0.0f;
        for (int w = 0; w < wid; ++w) pre += wpart[w];
        const float a = pcp_c * (pre + v);
        base[(size_t)q * KLEN + k] = a;
        aw = a;
        pcp_c = pcp_n;
        icp_c = icp_n;
        __syncthreads();                       // protect wpart reuse
    }
}

// beta[b,hca,q,k] = se * movsum_fwd3(alpha[b,hma,q,:]/den[b,hca,q,:]) for fixed hma
__global__ __launch_bounds__(256) void beta_kernel(
    const float* __restrict__ ALPHA, const float* __restrict__ SE,
    const float* __restrict__ DEN, float* __restrict__ BETA, int hma)
{
    const int rowi = blockIdx.x;               // ((b*H_CA)+hca)*QLEN + q
    const int q  = rowi & (QLEN - 1);
    const int bh = rowi >> 9;
    const int hca = bh & (H_CA - 1);
    const int b  = bh >> 1;

    const float* arow = ALPHA + ((((size_t)b * H_MA + hma) * QLEN + q) * KLEN);
    const float* srow = SE  + (size_t)rowi * KLEN;
    const float* drow = DEN + (size_t)rowi * KLEN;
    float* brow = BETA + (size_t)rowi * KLEN;

    __shared__ float ad[KLEN + CHUNK - 1];
    const int tid = threadIdx.x;
    const float4 a4 = *(const float4*)(arow + tid * 4);
    const float4 d4 = *(const float4*)(drow + tid * 4);
    const float ar[4] = {a4.x, a4.y, a4.z, a4.w};
    const float dr[4] = {d4.x, d4.y, d4.z, d4.w};
#pragma unroll
    for (int j = 0; j < 4; ++j)
        ad[tid * 4 + j] = ar[j] / dr[j];
    if (tid < CHUNK - 1) ad[KLEN + tid] = 0.0f;
    __syncthreads();

    const float4 s4 = *(const float4*)(srow + tid * 4);
    const float sr[4] = {s4.x, s4.y, s4.z, s4.w};
    float4 o;
    float* op = (float*)&o;
#pragma unroll
    for (int j = 0; j < 4; ++j) {
        const int k = tid * 4 + j;
        op[j] = sr[j] * (ad[k] + ad[k + 1] + ad[k + 2] + ad[k + 3]);
    }
    *(float4*)(brow + tid * 4) = o;
}

// cv[b, q, h*64..] += beta[b,hca] @ v_head   for fixed hma
__global__ __launch_bounds__(256) void cv_gemm_kernel(
    const float* __restrict__ BETA, const float* __restrict__ VP,
    float* __restrict__ CV, int hma)
{
    const int z = blockIdx.y;
    const int b = z / H_CA;
    const int hca = z - b * H_CA;
    const int h = hma * H_CA + hca;
    const float* A  = BETA + (size_t)z * QLEN * KLEN;       // lda = KLEN
    const float* Bm = VP + (size_t)b * KLEN * DIM + h * 64; // ldb = DIM
    float* C = CV + (size_t)b * QLEN * DIM + h * 64;        // ldc = DIM
    gemm_nn_tile(A, KLEN, Bm, DIM, C, DIM, KLEN, nullptr, blockIdx.x * 64, 0);
}

// ---------------------------------------------------------------------------

extern "C" void kernel_launch(void* const* d_in, const int* in_sizes, int n_in,
                              void* d_out, int out_size, void* d_ws, size_t ws_size,
                              hipStream_t stream)
{
    (void)in_sizes; (void)n_in; (void)out_size; (void)ws_size;
    const float* key_t = (const float*)d_in[0];
    const float* query = (const float*)d_in[1];
    const float* wk_ma = (const float*)d_in[2];
    const float* bk_ma = (const float*)d_in[3];
    const float* wq_ma = (const float*)d_in[4];
    const float* bq_ma = (const float*)d_in[5];
    const float* r     = (const float*)d_in[6];
    const float* wk_ca = (const float*)d_in[7];
    const float* bk_ca = (const float*)d_in[8];
    const float* wq_ca = (const float*)d_in[9];
    const float* bq_ca = (const float*)d_in[10];
    const float* wv    = (const float*)d_in[11];
    const float* bv    = (const float*)d_in[12];
    const float* wo    = (const float*)d_in[13];
    const float* bo    = (const float*)d_in[14];
    float* out = (float*)d_out;

    float* ws = (float*)d_ws;
    size_t off = 0;
    float* KP_MA = ws + off; off += (size_t)B_ * KLEN * DIM;
    float* QP_MA = ws + off; off += (size_t)B_ * QLEN * DIM;
    float* KP_CA = ws + off; off += (size_t)B_ * KLEN * DIM;
    float* QP_CA = ws + off; off += (size_t)B_ * QLEN * DIM;
    float* VP    = ws + off; off += (size_t)B_ * KLEN * DIM;
    float* PCP   = ws + off; off += (size_t)B_ * H_MA * QLEN * KLEN; // e_ma -> pcp -> alpha
    float* ICP   = ws + off; off += (size_t)B_ * H_MA * QLEN * KLEN;
    float* SE    = ws + off; off += (size_t)B_ * H_CA * QLEN * KLEN; // e_ca -> se
    float* DEN   = ws + off; off += (size_t)B_ * H_CA * QLEN * KLEN;
    float* BETA  = ws + off; off += (size_t)B_ * H_CA * QLEN * KLEN;
    float* CV    = ws + off; off += (size_t)B_ * QLEN * DIM;

    const dim3 blk(256);

    // projections (fp32 NN GEMMs, K=512)
    gemm_nn_kernel<<<dim3(B_ * KLEN / 64, DIM / 64), blk, 0, stream>>>(key_t, DIM, wk_ma, DIM, KP_MA, DIM, DIM, bk_ma);
    gemm_nn_kernel<<<dim3(B_ * QLEN / 64, DIM / 64), blk, 0, stream>>>(query, DIM, wq_ma, DIM, QP_MA, DIM, DIM, bq_ma);
    gemm_nn_kernel<<<dim3(B_ * KLEN / 64, DIM / 64), blk, 0, stream>>>(key_t, DIM, wk_ca, DIM, KP_CA, DIM, DIM, bk_ca);
    gemm_nn_kernel<<<dim3(B_ * QLEN / 64, DIM / 64), blk, 0, stream>>>(query, DIM, wq_ca, DIM, QP_CA, DIM, DIM, bq_ca);
    gemm_nn_kernel<<<dim3(B_ * KLEN / 64, DIM / 64), blk, 0, stream>>>(key_t, DIM, wv, DIM, VP, DIM, DIM, bv);

    // energies (NT batched over (b,h))
    energy_nt_kernel<<<dim3(QLEN / 64, KLEN / 64, B_ * H_MA), blk, 0, stream>>>(QP_MA, KP_MA, PCP, H_MA, DIM / H_MA, r);
    energy_nt_kernel<<<dim3(QLEN / 64, KLEN / 64, B_ * H_CA), blk, 0, stream>>>(QP_CA, KP_CA, SE, H_CA, DIM / H_CA, nullptr);

    // row transforms
    ma_row_kernel<<<dim3(B_ * H_MA * QLEN), blk, 0, stream>>>(PCP, ICP);
    ca_row_kernel<<<dim3(B_ * H_CA * QLEN), blk, 0, stream>>>(SE, DEN);

    // monotonic alignment recurrence (serial over q)
    alpha_kernel<<<dim3(B_ * H_MA), dim3(1024), 0, stream>>>(PCP, ICP);

    // beta + context GEMM, chunked over h_ma
    for (int hma = 0; hma < H_MA; ++hma) {
        beta_kernel<<<dim3(B_ * H_CA * QLEN), blk, 0, stream>>>(PCP, SE, DEN, BETA, hma);
        cv_gemm_kernel<<<dim3(QLEN / 64, B_ * H_CA), blk, 0, stream>>>(BETA, VP, CV, hma);
    }

    // output projection
    gemm_nn_kernel<<<dim3(B_ * QLEN / 64, DIM / 64), blk, 0, stream>>>(CV, DIM, wo, DIM, out, DIM, DIM, bo);
}

// Round 2
// 745.011 us; speedup vs baseline: 1.4699x; 1.4699x over previous
//
#include <hip/hip_runtime.h>
#include <hip/hip_bf16.h>
#include <math.h>

#define DEV_INLINE __device__ __forceinline__

constexpr int B_    = 4;
constexpr int QLEN  = 512;
constexpr int KLEN  = 1024;
constexpr int DIM   = 512;
constexpr int H_MA  = 4;
constexpr int H_CA  = 2;
constexpr int CHUNK = 4;
constexpr float EPS = 1e-6f;
constexpr float INV_SCALE = 1.0f / 22.62741699796952f;  // 1/sqrt(512)

// ---------------------------------------------------------------------------
// Generic 64x64 fp32 GEMM tiles (BK=16, 256 threads, 4x4 per thread)
// ---------------------------------------------------------------------------

// C[bm..bm+64, bn..bn+64] = A[M,K] @ B[K,N] (+bias), all row-major.
DEV_INLINE void gemm_nn_tile(const float* __restrict__ A, int lda,
                             const float* __restrict__ Bm, int ldb,
                             float* __restrict__ C, int ldc,
                             int K, const float* __restrict__ bias,
                             int bm, int bn)
{
    __shared__ float As[16][68];
    __shared__ float Bs[16][68];
    const int tid  = threadIdx.x;
    const int tm   = (tid >> 4) << 2;   // 0..60
    const int tn   = (tid & 15) << 2;   // 0..60
    const int arow = tid >> 2;          // 0..63
    const int acol = (tid & 3) << 2;    // 0,4,8,12
    const int brow = tid >> 4;          // 0..15
    const int bcol = (tid & 15) << 2;   // 0..60
    float acc[4][4] = {};

    for (int k0 = 0; k0 < K; k0 += 16) {
        const float4 av = *(const float4*)(A + (size_t)(bm + arow) * lda + k0 + acol);
        const float4 bv = *(const float4*)(Bm + (size_t)(k0 + brow) * ldb + bn + bcol);
        __syncthreads();
        As[acol + 0][arow] = av.x;
        As[acol + 1][arow] = av.y;
        As[acol + 2][arow] = av.z;
        As[acol + 3][arow] = av.w;
        *(float4*)(&Bs[brow][bcol]) = bv;
        __syncthreads();
#pragma unroll
        for (int kk = 0; kk < 16; ++kk) {
            const float4 a = *(const float4*)&As[kk][tm];
            const float4 b = *(const float4*)&Bs[kk][tn];
            const float ar[4] = {a.x, a.y, a.z, a.w};
            const float br[4] = {b.x, b.y, b.z, b.w};
#pragma unroll
            for (int i = 0; i < 4; ++i)
#pragma unroll
                for (int j = 0; j < 4; ++j)
                    acc[i][j] = fmaf(ar[i], br[j], acc[i][j]);
        }
    }
#pragma unroll
    for (int i = 0; i < 4; ++i) {
        float4 o;
        float* op = (float*)&o;
#pragma unroll
        for (int j = 0; j < 4; ++j)
            op[j] = acc[i][j] + (bias ? bias[bn + tn + j] : 0.0f);
        *(float4*)(C + (size_t)(bm + tm + i) * ldc + bn + tn) = o;
    }
}

// C[bm.., bn..] = A[M,K] @ B[N,K]^T * scale + addv  (both operands k-inner)
DEV_INLINE void gemm_nt_tile(const float* __restrict__ A, int lda,
                             const float* __restrict__ Bm, int ldb,
                             float* __restrict__ C, int ldc,
                             int K, float scale, float addv,
                             int bm, int bn)
{
    __shared__ float As[16][68];
    __shared__ float Bs[16][68];
    const int tid = threadIdx.x;
    const int tm  = (tid >> 4) << 2;
    const int tn  = (tid & 15) << 2;
    const int row = tid >> 2;          // 0..63
    const int col = (tid & 3) << 2;    // 0,4,8,12
    float acc[4][4] = {};

    for (int k0 = 0; k0 < K; k0 += 16) {
        const float4 av = *(const float4*)(A + (size_t)(bm + row) * lda + k0 + col);
        const float4 bv = *(const float4*)(Bm + (size_t)(bn + row) * ldb + k0 + col);
        __syncthreads();
        As[col + 0][row] = av.x;
        As[col + 1][row] = av.y;
        As[col + 2][row] = av.z;
        As[col + 3][row] = av.w;
        Bs[col + 0][row] = bv.x;
        Bs[col + 1][row] = bv.y;
        Bs[col + 2][row] = bv.z;
        Bs[col + 3][row] = bv.w;
        __syncthreads();
#pragma unroll
        for (int kk = 0; kk < 16; ++kk) {
            const float4 a = *(const float4*)&As[kk][tm];
            const float4 b = *(const float4*)&Bs[kk][tn];
            const float ar[4] = {a.x, a.y, a.z, a.w};
            const float br[4] = {b.x, b.y, b.z, b.w};
#pragma unroll
            for (int i = 0; i < 4; ++i)
#pragma unroll
                for (int j = 0; j < 4; ++j)
                    acc[i][j] = fmaf(ar[i], br[j], acc[i][j]);
        }
    }
#pragma unroll
    for (int i = 0; i < 4; ++i) {
        float4 o;
        float* op = (float*)&o;
#pragma unroll
        for (int j = 0; j < 4; ++j)
            op[j] = acc[i][j] * scale + addv;
        *(float4*)(C + (size_t)(bm + tm + i) * ldc + bn + tn) = o;
    }
}

// ---------------------------------------------------------------------------
// Kernels
// ---------------------------------------------------------------------------

__global__ __launch_bounds__(256) void gemm_nn_kernel(
    const float* __restrict__ A, int lda,
    const float* __restrict__ Bm, int ldb,
    float* __restrict__ C, int ldc,
    int K, const float* __restrict__ bias)
{
    gemm_nn_tile(A, lda, Bm, ldb, C, ldc, K, bias, blockIdx.x * 64, blockIdx.y * 64);
}

// e[z, q, k] = (QP[b,q,h*HD:+HD] . KP[b,k,h*HD:+HD]) / SCALE + (radd ? radd[0] : 0)
__global__ __launch_bounds__(256) void energy_nt_kernel(
    const float* __restrict__ QP, const float* __restrict__ KP,
    float* __restrict__ E, int H, int HD, const float* __restrict__ radd)
{
    const int z = blockIdx.z;
    const int b = z / H;
    const int h = z - b * H;
    const float* A  = QP + (size_t)b * QLEN * DIM + h * HD;
    const float* Bm = KP + (size_t)b * KLEN * DIM + h * HD;
    float* C = E + (size_t)z * QLEN * KLEN;
    const float addv = radd ? radd[0] : 0.0f;
    gemm_nt_tile(A, DIM, Bm, DIM, C, KLEN, HD, INV_SCALE, addv,
                 blockIdx.x * 64, blockIdx.y * 64);
}

// in-place: PCP holds e_ma rows on input; writes pcp = p*cp and icp = 1/max(cp,EPS)
__global__ __launch_bounds__(256) void ma_row_kernel(float* __restrict__ PCP,
                                                     float* __restrict__ ICP)
{
    const size_t row = blockIdx.x;
    float* pe = PCP + row * KLEN;
    float* pi = ICP + row * KLEN;
    const int tid = threadIdx.x;
    const int lane = tid & 63, wid = tid >> 6;

    const float4 ev = *(const float4*)(pe + tid * 4);
    float e[4] = {ev.x, ev.y, ev.z, ev.w};
    float p[4], l[4], s[4];
    float run = 0.0f;
#pragma unroll
    for (int j = 0; j < 4; ++j) {
        p[j] = 1.0f / (1.0f + expf(-e[j]));
        float om = 1.0f - p[j];
        om = fminf(fmaxf(om, EPS), 1.0f);
        l[j] = logf(om);
        run += l[j];
        s[j] = run;
    }
    const float t = run;
    float v = t;
#pragma unroll
    for (int off = 1; off < 64; off <<= 1) {
        const float u = __shfl_up(v, off);
        if (lane >= off) v += u;
    }
    __shared__ float wsum[4];
    if (lane == 63) wsum[wid] = v;
    __syncthreads();
    float base = v - t;
    for (int w = 0; w < wid; ++w) base += wsum[w];

    float4 po, io;
    float* pp = (float*)&po;
    float* ip = (float*)&io;
#pragma unroll
    for (int j = 0; j < 4; ++j) {
        const float cum = base + s[j];               // inclusive cumsum of log1mp
        const float cp  = expf(cum - l[j]);          // exclusive cumprod
        pp[j] = p[j] * cp;
        ip[j] = 1.0f / fmaxf(cp, EPS);
    }
    *(float4*)(pe + tid * 4) = po;
    *(float4*)(pi + tid * 4) = io;
}

// in-place: SE holds e_ca rows on input; writes se and denom (moving sum back=3)
__global__ __launch_bounds__(256) void ca_row_kernel(float* __restrict__ SE,
                                                     float* __restrict__ DEN)
{
    const size_t row = blockIdx.x;
    float* ps = SE + row * KLEN;
    float* pd = DEN + row * KLEN;
    const int tid = threadIdx.x;
    const int lane = tid & 63, wid = tid >> 6;

    const float4 ev = *(const float4*)(ps + tid * 4);
    float e[4] = {ev.x, ev.y, ev.z, ev.w};
    float m = fmaxf(fmaxf(e[0], e[1]), fmaxf(e[2], e[3]));
#pragma unroll
    for (int off = 32; off >= 1; off >>= 1)
        m = fmaxf(m, __shfl_xor(m, off));
    __shared__ float wmax[4];
    if (lane == 0) wmax[wid] = m;
    __syncthreads();
    m = fmaxf(fmaxf(wmax[0], wmax[1]), fmaxf(wmax[2], wmax[3]));

    __shared__ float sh[KLEN + 3];   // sh[3+k] = se[k], sh[0..2] = 0
    if (tid < 3) sh[tid] = 0.0f;
    float se[4];
#pragma unroll
    for (int j = 0; j < 4; ++j) {
        se[j] = fmaxf(expf(e[j] - m), 1e-5f);
        sh[3 + tid * 4 + j] = se[j];
    }
    __syncthreads();
    float4 so, do_;
    float* sp = (float*)&so;
    float* dp = (float*)&do_;
#pragma unroll
    for (int j = 0; j < 4; ++j) {
        const int k = tid * 4 + j;
        sp[j] = se[j];
        dp[j] = sh[3 + k] + sh[2 + k] + sh[1 + k] + sh[k];
    }
    *(float4*)(ps + tid * 4) = so;
    *(float4*)(pd + tid * 4) = do_;
}

// ---------------------------------------------------------------------------
// alpha recurrence: single wave per (b,h_ma), DPP wave scan, register state.
// PCP buffer initially holds pcp rows, overwritten with alpha.
// ---------------------------------------------------------------------------

template<int CTRL, int ROW_MASK>
DEV_INLINE float dpp_add(float x) {
    // t = dpp_move(x); invalid/masked-out lanes contribute 0 (old = 0, bound_ctrl)
    int t = __builtin_amdgcn_update_dpp(0, __float_as_int(x), CTRL, ROW_MASK, 0xf, true);
    return x + __int_as_float(t);
}

DEV_INLINE float wave64_incl_scan(float x) {
    x = dpp_add<0x111, 0xf>(x);  // row_shr:1
    x = dpp_add<0x112, 0xf>(x);  // row_shr:2
    x = dpp_add<0x114, 0xf>(x);  // row_shr:4
    x = dpp_add<0x118, 0xf>(x);  // row_shr:8
    x = dpp_add<0x142, 0xa>(x);  // row_bcast:15 -> rows 1,3
    x = dpp_add<0x143, 0xc>(x);  // row_bcast:31 -> rows 2,3
    return x;
}

constexpr int PF = 4;  // prefetch depth in rows (static ring, fully unrolled)

__global__ __launch_bounds__(64) void alpha_kernel(float* __restrict__ PCP,
                                                   const float* __restrict__ ICP)
{
    const int z = blockIdx.x;                 // (b, h_ma)
    float* base = PCP + (size_t)z * QLEN * KLEN;
    const float* ibase = ICP + (size_t)z * QLEN * KLEN;
    const int lane = threadIdx.x;             // 0..63
    const int col = lane * 16;

    float pcp[PF][16], icp[PF][16];
#pragma unroll
    for (int i = 0; i < PF; ++i) {
#pragma unroll
        for (int v = 0; v < 4; ++v) {
            *(float4*)&pcp[i][v * 4] = *(const float4*)(base + (size_t)i * KLEN + col + v * 4);
            *(float4*)&icp[i][v * 4] = *(const float4*)(ibase + (size_t)i * KLEN + col + v * 4);
        }
    }

    float a[16];
#pragma unroll
    for (int j = 0; j < 16; ++j) a[j] = 0.0f;
    if (lane == 0) a[0] = 1.0f;

    for (int q0 = 0; q0 < QLEN; q0 += PF) {
#pragma unroll
        for (int i = 0; i < PF; ++i) {
            const int q = q0 + i;
            float t[16];
#pragma unroll
            for (int j = 0; j < 16; ++j) t[j] = a[j] * icp[i][j];

            // lane total via pairwise tree (short critical path)
            float u1[8], u2[4], u3[2];
#pragma unroll
            for (int j = 0; j < 8; ++j) u1[j] = t[2 * j] + t[2 * j + 1];
#pragma unroll
            for (int j = 0; j < 4; ++j) u2[j] = u1[2 * j] + u1[2 * j + 1];
            u3[0] = u2[0] + u2[1];
            u3[1] = u2[2] + u2[3];
            const float tot = u3[0] + u3[1];

            const float incl = wave64_incl_scan(tot);
            const float excl = incl - tot;

            // per-lane inclusive prefix (overlaps with the DPP scan)
            float s[16];
            s[0] = t[0];
#pragma unroll
            for (int j = 1; j < 16; ++j) s[j] = s[j - 1] + t[j];

#pragma unroll
            for (int j = 0; j < 16; ++j) a[j] = pcp[i][j] * (excl + s[j]);

            float* orow = base + (size_t)q * KLEN + col;
#pragma unroll
            for (int v = 0; v < 4; ++v)
                *(float4*)(orow + v * 4) = *(const float4*)&a[v * 4];

            // prefetch row q+PF into slot i (statically indexed)
            if (q + PF < QLEN) {
                const float* prow = base + (size_t)(q + PF) * KLEN + col;
                const float* irow = ibase + (size_t)(q + PF) * KLEN + col;
#pragma unroll
                for (int v = 0; v < 4; ++v) {
                    *(float4*)&pcp[i][v * 4] = *(const float4*)(prow + v * 4);
                    *(float4*)&icp[i][v * 4] = *(const float4*)(irow + v * 4);
                }
            }
        }
    }
}

// beta[b,hca,q,k] = se * movsum_fwd3(alpha[b,hma,q,:]/den[b,hca,q,:]) for fixed hma
__global__ __launch_bounds__(256) void beta_kernel(
    const float* __restrict__ ALPHA, const float* __restrict__ SE,
    const float* __restrict__ DEN, float* __restrict__ BETA, int hma)
{
    const int rowi = blockIdx.x;               // ((b*H_CA)+hca)*QLEN + q
    const int q  = rowi & (QLEN - 1);
    const int bh = rowi >> 9;
    const int hca = bh & (H_CA - 1);
    const int b  = bh >> 1;

    const float* arow = ALPHA + ((((size_t)b * H_MA + hma) * QLEN + q) * KLEN);
    const float* srow = SE  + (size_t)rowi * KLEN;
    const float* drow = DEN + (size_t)rowi * KLEN;
    float* brow = BETA + (size_t)rowi * KLEN;

    __shared__ float ad[KLEN + CHUNK - 1];
    const int tid = threadIdx.x;
    const float4 a4 = *(const float4*)(arow + tid * 4);
    const float4 d4 = *(const float4*)(drow + tid * 4);
    const float ar[4] = {a4.x, a4.y, a4.z, a4.w};
    const float dr[4] = {d4.x, d4.y, d4.z, d4.w};
#pragma unroll
    for (int j = 0; j < 4; ++j)
        ad[tid * 4 + j] = ar[j] / dr[j];
    if (tid < CHUNK - 1) ad[KLEN + tid] = 0.0f;
    __syncthreads();

    const float4 s4 = *(const float4*)(srow + tid * 4);
    const float sr[4] = {s4.x, s4.y, s4.z, s4.w};
    float4 o;
    float* op = (float*)&o;
#pragma unroll
    for (int j = 0; j < 4; ++j) {
        const int k = tid * 4 + j;
        op[j] = sr[j] * (ad[k] + ad[k + 1] + ad[k + 2] + ad[k + 3]);
    }
    *(float4*)(brow + tid * 4) = o;
}

// cv[b, q, h*64..] += beta[b,hca] @ v_head   for fixed hma
__global__ __launch_bounds__(256) void cv_gemm_kernel(
    const float* __restrict__ BETA, const float* __restrict__ VP,
    float* __restrict__ CV, int hma)
{
    const int z = blockIdx.y;
    const int b = z / H_CA;
    const int hca = z - b * H_CA;
    const int h = hma * H_CA + hca;
    const float* A  = BETA + (size_t)z * QLEN * KLEN;       // lda = KLEN
    const float* Bm = VP + (size_t)b * KLEN * DIM + h * 64; // ldb = DIM
    float* C = CV + (size_t)b * QLEN * DIM + h * 64;        // ldc = DIM
    gemm_nn_tile(A, KLEN, Bm, DIM, C, DIM, KLEN, nullptr, blockIdx.x * 64, 0);
}

// ---------------------------------------------------------------------------

extern "C" void kernel_launch(void* const* d_in, const int* in_sizes, int n_in,
                              void* d_out, int out_size, void* d_ws, size_t ws_size,
                              hipStream_t stream)
{
    (void)in_sizes; (void)n_in; (void)out_size; (void)ws_size;
    const float* key_t = (const float*)d_in[0];
    const float* query = (const float*)d_in[1];
    const float* wk_ma = (const float*)d_in[2];
    const float* bk_ma = (const float*)d_in[3];
    const float* wq_ma = (const float*)d_in[4];
    const float* bq_ma = (const float*)d_in[5];
    const float* r     = (const float*)d_in[6];
    const float* wk_ca = (const float*)d_in[7];
    const float* bk_ca = (const float*)d_in[8];
    const float* wq_ca = (const float*)d_in[9];
    const float* bq_ca = (const float*)d_in[10];
    const float* wv    = (const float*)d_in[11];
    const float* bv    = (const float*)d_in[12];
    const float* wo    = (const float*)d_in[13];
    const float* bo    = (const float*)d_in[14];
    float* out = (float*)d_out;

    float* ws = (float*)d_ws;
    size_t off = 0;
    float* KP_MA = ws + off; off += (size_t)B_ * KLEN * DIM;
    float* QP_MA = ws + off; off += (size_t)B_ * QLEN * DIM;
    float* KP_CA = ws + off; off += (size_t)B_ * KLEN * DIM;
    float* QP_CA = ws + off; off += (size_t)B_ * QLEN * DIM;
    float* VP    = ws + off; off += (size_t)B_ * KLEN * DIM;
    float* PCP   = ws + off; off += (size_t)B_ * H_MA * QLEN * KLEN; // e_ma -> pcp -> alpha
    float* ICP   = ws + off; off += (size_t)B_ * H_MA * QLEN * KLEN;
    float* SE    = ws + off; off += (size_t)B_ * H_CA * QLEN * KLEN; // e_ca -> se
    float* DEN   = ws + off; off += (size_t)B_ * H_CA * QLEN * KLEN;
    float* BETA  = ws + off; off += (size_t)B_ * H_CA * QLEN * KLEN;
    float* CV    = ws + off; off += (size_t)B_ * QLEN * DIM;

    const dim3 blk(256);

    // projections (fp32 NN GEMMs, K=512)
    gemm_nn_kernel<<<dim3(B_ * KLEN / 64, DIM / 64), blk, 0, stream>>>(key_t, DIM, wk_ma, DIM, KP_MA, DIM, DIM, bk_ma);
    gemm_nn_kernel<<<dim3(B_ * QLEN / 64, DIM / 64), blk, 0, stream>>>(query, DIM, wq_ma, DIM, QP_MA, DIM, DIM, bq_ma);
    gemm_nn_kernel<<<dim3(B_ * KLEN / 64, DIM / 64), blk, 0, stream>>>(key_t, DIM, wk_ca, DIM, KP_CA, DIM, DIM, bk_ca);
    gemm_nn_kernel<<<dim3(B_ * QLEN / 64, DIM / 64), blk, 0, stream>>>(query, DIM, wq_ca, DIM, QP_CA, DIM, DIM, bq_ca);
    gemm_nn_kernel<<<dim3(B_ * KLEN / 64, DIM / 64), blk, 0, stream>>>(key_t, DIM, wv, DIM, VP, DIM, DIM, bv);

    // energies (NT batched over (b,h))
    energy_nt_kernel<<<dim3(QLEN / 64, KLEN / 64, B_ * H_MA), blk, 0, stream>>>(QP_MA, KP_MA, PCP, H_MA, DIM / H_MA, r);
    energy_nt_kernel<<<dim3(QLEN / 64, KLEN / 64, B_ * H_CA), blk, 0, stream>>>(QP_CA, KP_CA, SE, H_CA, DIM / H_CA, nullptr);

    // row transforms
    ma_row_kernel<<<dim3(B_ * H_MA * QLEN), blk, 0, stream>>>(PCP, ICP);
    ca_row_kernel<<<dim3(B_ * H_CA * QLEN), blk, 0, stream>>>(SE, DEN);

    // monotonic alignment recurrence (single wave per (b,h), DPP scan)
    alpha_kernel<<<dim3(B_ * H_MA), dim3(64), 0, stream>>>(PCP, ICP);

    // beta + context GEMM, chunked over h_ma
    for (int hma = 0; hma < H_MA; ++hma) {
        beta_kernel<<<dim3(B_ * H_CA * QLEN), blk, 0, stream>>>(PCP, SE, DEN, BETA, hma);
        cv_gemm_kernel<<<dim3(QLEN / 64, B_ * H_CA), blk, 0, stream>>>(BETA, VP, CV, hma);
    }

    // output projection
    gemm_nn_kernel<<<dim3(B_ * QLEN / 64, DIM / 64), blk, 0, stream>>>(CV, DIM, wo, DIM, out, DIM, DIM, bo);
}

// Round 8
// 707.959 us; speedup vs baseline: 1.5469x; 1.0523x over previous
//
#include <hip/hip_runtime.h>
#include <hip/hip_bf16.h>
#include <math.h>

#define DEV_INLINE __device__ __forceinline__

typedef float f32x4 __attribute__((ext_vector_type(4)));

constexpr int B_    = 4;
constexpr int QLEN  = 512;
constexpr int KLEN  = 1024;
constexpr int DIM   = 512;
constexpr int H_MA  = 4;
constexpr int H_CA  = 2;
constexpr int CHUNK = 4;
constexpr float EPS = 1e-6f;
constexpr float INV_SCALE = 1.0f / 22.62741699796952f;  // 1/sqrt(512)

// ---------------------------------------------------------------------------
// Generic 64x64 fp32 GEMM tiles (BK=16, 256 threads, 4x4 per thread)
// ---------------------------------------------------------------------------

DEV_INLINE void gemm_nn_tile(const float* __restrict__ A, int lda,
                             const float* __restrict__ Bm, int ldb,
                             float* __restrict__ C, int ldc,
                             int K, const float* __restrict__ bias,
                             int bm, int bn)
{
    __shared__ float As[16][68];
    __shared__ float Bs[16][68];
    const int tid  = threadIdx.x;
    const int tm   = (tid >> 4) << 2;
    const int tn   = (tid & 15) << 2;
    const int arow = tid >> 2;
    const int acol = (tid & 3) << 2;
    const int brow = tid >> 4;
    const int bcol = (tid & 15) << 2;
    float acc[4][4] = {};

    for (int k0 = 0; k0 < K; k0 += 16) {
        const float4 av = *(const float4*)(A + (size_t)(bm + arow) * lda + k0 + acol);
        const float4 bv = *(const float4*)(Bm + (size_t)(k0 + brow) * ldb + bn + bcol);
        __syncthreads();
        As[acol + 0][arow] = av.x;
        As[acol + 1][arow] = av.y;
        As[acol + 2][arow] = av.z;
        As[acol + 3][arow] = av.w;
        *(float4*)(&Bs[brow][bcol]) = bv;
        __syncthreads();
#pragma unroll
        for (int kk = 0; kk < 16; ++kk) {
            const float4 a = *(const float4*)&As[kk][tm];
            const float4 b = *(const float4*)&Bs[kk][tn];
            const float ar[4] = {a.x, a.y, a.z, a.w};
            const float br[4] = {b.x, b.y, b.z, b.w};
#pragma unroll
            for (int i = 0; i < 4; ++i)
#pragma unroll
                for (int j = 0; j < 4; ++j)
                    acc[i][j] = fmaf(ar[i], br[j], acc[i][j]);
        }
    }
#pragma unroll
    for (int i = 0; i < 4; ++i) {
        float4 o;
        float* op = (float*)&o;
#pragma unroll
        for (int j = 0; j < 4; ++j)
            op[j] = acc[i][j] + (bias ? bias[bn + tn + j] : 0.0f);
        *(float4*)(C + (size_t)(bm + tm + i) * ldc + bn + tn) = o;
    }
}

DEV_INLINE void gemm_nt_tile(const float* __restrict__ A, int lda,
                             const float* __restrict__ Bm, int ldb,
                             float* __restrict__ C, int ldc,
                             int K, float scale, float addv,
                             int bm, int bn)
{
    __shared__ float As[16][68];
    __shared__ float Bs[16][68];
    const int tid = threadIdx.x;
    const int tm  = (tid >> 4) << 2;
    const int tn  = (tid & 15) << 2;
    const int row = tid >> 2;
    const int col = (tid & 3) << 2;
    float acc[4][4] = {};

    for (int k0 = 0; k0 < K; k0 += 16) {
        const float4 av = *(const float4*)(A + (size_t)(bm + row) * lda + k0 + col);
        const float4 bv = *(const float4*)(Bm + (size_t)(bn + row) * ldb + k0 + col);
        __syncthreads();
        As[col + 0][row] = av.x;
        As[col + 1][row] = av.y;
        As[col + 2][row] = av.z;
        As[col + 3][row] = av.w;
        Bs[col + 0][row] = bv.x;
        Bs[col + 1][row] = bv.y;
        Bs[col + 2][row] = bv.z;
        Bs[col + 3][row] = bv.w;
        __syncthreads();
#pragma unroll
        for (int kk = 0; kk < 16; ++kk) {
            const float4 a = *(const float4*)&As[kk][tm];
            const float4 b = *(const float4*)&Bs[kk][tn];
            const float ar[4] = {a.x, a.y, a.z, a.w};
            const float br[4] = {b.x, b.y, b.z, b.w};
#pragma unroll
            for (int i = 0; i < 4; ++i)
#pragma unroll
                for (int j = 0; j < 4; ++j)
                    acc[i][j] = fmaf(ar[i], br[j], acc[i][j]);
        }
    }
#pragma unroll
    for (int i = 0; i < 4; ++i) {
        float4 o;
        float* op = (float*)&o;
#pragma unroll
        for (int j = 0; j < 4; ++j)
            op[j] = acc[i][j] * scale + addv;
        *(float4*)(C + (size_t)(bm + tm + i) * ldc + bn + tn) = o;
    }
}

// ---------------------------------------------------------------------------

__global__ __launch_bounds__(256) void gemm_nn_kernel(
    const float* __restrict__ A, int lda,
    const float* __restrict__ Bm, int ldb,
    float* __restrict__ C, int ldc,
    int K, const float* __restrict__ bias)
{
    gemm_nn_tile(A, lda, Bm, ldb, C, ldc, K, bias, blockIdx.x * 64, blockIdx.y * 64);
}

__global__ __launch_bounds__(256) void energy_nt_kernel(
    const float* __restrict__ QP, const float* __restrict__ KP,
    float* __restrict__ E, int H, int HD, const float* __restrict__ radd)
{
    const int z = blockIdx.z;
    const int b = z / H;
    const int h = z - b * H;
    const float* A  = QP + (size_t)b * QLEN * DIM + h * HD;
    const float* Bm = KP + (size_t)b * KLEN * DIM + h * HD;
    float* C = E + (size_t)z * QLEN * KLEN;
    const float addv = radd ? radd[0] : 0.0f;
    gemm_nt_tile(A, DIM, Bm, DIM, C, KLEN, HD, INV_SCALE, addv,
                 blockIdx.x * 64, blockIdx.y * 64);
}

__global__ __launch_bounds__(256) void ma_row_kernel(float* __restrict__ PCP,
                                                     float* __restrict__ ICP)
{
    const size_t row = blockIdx.x;
    float* pe = PCP + row * KLEN;
    float* pi = ICP + row * KLEN;
    const int tid = threadIdx.x;
    const int lane = tid & 63, wid = tid >> 6;

    const float4 ev = *(const float4*)(pe + tid * 4);
    float e[4] = {ev.x, ev.y, ev.z, ev.w};
    float p[4], l[4], s[4];
    float run = 0.0f;
#pragma unroll
    for (int j = 0; j < 4; ++j) {
        p[j] = 1.0f / (1.0f + expf(-e[j]));
        float om = 1.0f - p[j];
        om = fminf(fmaxf(om, EPS), 1.0f);
        l[j] = logf(om);
        run += l[j];
        s[j] = run;
    }
    const float t = run;
    float v = t;
#pragma unroll
    for (int off = 1; off < 64; off <<= 1) {
        const float u = __shfl_up(v, off);
        if (lane >= off) v += u;
    }
    __shared__ float wsum[4];
    if (lane == 63) wsum[wid] = v;
    __syncthreads();
    float base = v - t;
    for (int w = 0; w < wid; ++w) base += wsum[w];

    float4 po, io;
    float* pp = (float*)&po;
    float* ip = (float*)&io;
#pragma unroll
    for (int j = 0; j < 4; ++j) {
        const float cum = base + s[j];
        const float cp  = expf(cum - l[j]);
        pp[j] = p[j] * cp;
        ip[j] = 1.0f / fmaxf(cp, EPS);
    }
    *(float4*)(pe + tid * 4) = po;
    *(float4*)(pi + tid * 4) = io;
}

__global__ __launch_bounds__(256) void ca_row_kernel(float* __restrict__ SE,
                                                     float* __restrict__ DEN)
{
    const size_t row = blockIdx.x;
    float* ps = SE + row * KLEN;
    float* pd = DEN + row * KLEN;
    const int tid = threadIdx.x;
    const int lane = tid & 63, wid = tid >> 6;

    const float4 ev = *(const float4*)(ps + tid * 4);
    float e[4] = {ev.x, ev.y, ev.z, ev.w};
    float m = fmaxf(fmaxf(e[0], e[1]), fmaxf(e[2], e[3]));
#pragma unroll
    for (int off = 32; off >= 1; off >>= 1)
        m = fmaxf(m, __shfl_xor(m, off));
    __shared__ float wmax[4];
    if (lane == 0) wmax[wid] = m;
    __syncthreads();
    m = fmaxf(fmaxf(wmax[0], wmax[1]), fmaxf(wmax[2], wmax[3]));

    __shared__ float sh[KLEN + 3];
    if (tid < 3) sh[tid] = 0.0f;
    float se[4];
#pragma unroll
    for (int j = 0; j < 4; ++j) {
        se[j] = fmaxf(expf(e[j] - m), 1e-5f);
        sh[3 + tid * 4 + j] = se[j];
    }
    __syncthreads();
    float4 so, do_;
    float* sp = (float*)&so;
    float* dp = (float*)&do_;
#pragma unroll
    for (int j = 0; j < 4; ++j) {
        const int k = tid * 4 + j;
        sp[j] = se[j];
        dp[j] = sh[3 + k] + sh[2 + k] + sh[1 + k] + sh[k];
    }
    *(float4*)(ps + tid * 4) = so;
    *(float4*)(pd + tid * 4) = do_;
}

// ---------------------------------------------------------------------------
// alpha recurrence: single wave per (b,h_ma), DPP wave scan.
// Prefetch via 8-deep LDS ring filled by global_load_lds (no dest registers
// => no regalloc hazard). Per-lane transposed DMA source, linear LDS dest;
// reads are contiguous ds_read_b128. Register ping-pong (A/B) hides LDS
// latency under the scan. Counted vmcnt only (conservative with stores in
// the counter: total<=N forces loads<=N; loads retire in order).
// ---------------------------------------------------------------------------

template<int CTRL, int ROW_MASK>
DEV_INLINE float dpp_add(float x) {
    int t = __builtin_amdgcn_update_dpp(0, __float_as_int(x), CTRL, ROW_MASK, 0xf, true);
    return x + __int_as_float(t);
}

DEV_INLINE float wave64_incl_scan(float x) {
    x = dpp_add<0x111, 0xf>(x);  // row_shr:1
    x = dpp_add<0x112, 0xf>(x);  // row_shr:2
    x = dpp_add<0x114, 0xf>(x);  // row_shr:4
    x = dpp_add<0x118, 0xf>(x);  // row_shr:8
    x = dpp_add<0x142, 0xa>(x);  // row_bcast:15 -> rows 1,3
    x = dpp_add<0x143, 0xc>(x);  // row_bcast:31 -> rows 2,3
    return x;
}

typedef __attribute__((address_space(3))) void lv_t;
typedef __attribute__((address_space(1))) const void gv_t;

DEV_INLINE void dma16(const float* g, float* l) {
    __builtin_amdgcn_global_load_lds((gv_t*)g, (lv_t*)l, 16, 0, 0);
}

template<int N> DEV_INLINE void vwait() {
    asm volatile("s_waitcnt vmcnt(%0)" :: "i"(N) : "memory");
    __builtin_amdgcn_sched_barrier(0);
}

DEV_INLINE void alpha_step(const f32x4& P0, const f32x4& P1,
                           const f32x4& P2, const f32x4& P3,
                           const f32x4& I0, const f32x4& I1,
                           const f32x4& I2, const f32x4& I3,
                           float (&a)[16])
{
    float pc[16], ic[16];
    *(f32x4*)&pc[0] = P0; *(f32x4*)&pc[4] = P1;
    *(f32x4*)&pc[8] = P2; *(f32x4*)&pc[12] = P3;
    *(f32x4*)&ic[0] = I0; *(f32x4*)&ic[4] = I1;
    *(f32x4*)&ic[8] = I2; *(f32x4*)&ic[12] = I3;

    float t[16];
#pragma unroll
    for (int j = 0; j < 16; ++j) t[j] = a[j] * ic[j];

    float u1[8], u2[4];
#pragma unroll
    for (int j = 0; j < 8; ++j) u1[j] = t[2 * j] + t[2 * j + 1];
#pragma unroll
    for (int j = 0; j < 4; ++j) u2[j] = u1[2 * j] + u1[2 * j + 1];
    const float tot = (u2[0] + u2[1]) + (u2[2] + u2[3]);

    const float incl = wave64_incl_scan(tot);
    const float excl = incl - tot;

    float s = 0.0f;
#pragma unroll
    for (int j = 0; j < 16; ++j) {
        s += t[j];
        a[j] = pc[j] * (excl + s);
    }
}

// DMA one row-pair into ring buffer b. prow/irow include +lane*16.
// chunk c: lane l writes LDS floats [c*256 + l*4 .. +3] <- global [l*16+c*4 ..]
#define DMA_ROW(b, prow, irow)                        \
    dma16((prow) + 0,  &ring[b][0][0]);               \
    dma16((prow) + 4,  &ring[b][0][256]);             \
    dma16((prow) + 8,  &ring[b][0][512]);             \
    dma16((prow) + 12, &ring[b][0][768]);             \
    dma16((irow) + 0,  &ring[b][1][0]);               \
    dma16((irow) + 4,  &ring[b][1][256]);             \
    dma16((irow) + 8,  &ring[b][1][512]);             \
    dma16((irow) + 12, &ring[b][1][768]);

// lane reads its 16 floats: block j at ring[b][t][j*256 + lane*4]
#define READ_ROW(b, G)                                   \
    p##G##0 = *(const f32x4*)&ring[b][0][0   + l4];      \
    p##G##1 = *(const f32x4*)&ring[b][0][256 + l4];      \
    p##G##2 = *(const f32x4*)&ring[b][0][512 + l4];      \
    p##G##3 = *(const f32x4*)&ring[b][0][768 + l4];      \
    i##G##0 = *(const f32x4*)&ring[b][1][0   + l4];      \
    i##G##1 = *(const f32x4*)&ring[b][1][256 + l4];      \
    i##G##2 = *(const f32x4*)&ring[b][1][512 + l4];      \
    i##G##3 = *(const f32x4*)&ring[b][1][768 + l4];

// one step: wait row q+1 landed; ds_read it into group NG; compute group CG
// (row q); store; DMA row q+8 into the buffer just consumed (BUFC).
#define STEP(WAITN, BUFC, BUFN, DO_READ, DO_DMA, CG, NG)              \
    {                                                                 \
        vwait<WAITN>();                                               \
        if (DO_READ) { READ_ROW(BUFN, NG) }                           \
        alpha_step(p##CG##0, p##CG##1, p##CG##2, p##CG##3,            \
                   i##CG##0, i##CG##1, i##CG##2, i##CG##3, a);        \
        *(f32x4*)(st + 0)  = *(const f32x4*)&a[0];                    \
        *(f32x4*)(st + 4)  = *(const f32x4*)&a[4];                    \
        *(f32x4*)(st + 8)  = *(const f32x4*)&a[8];                    \
        *(f32x4*)(st + 12) = *(const f32x4*)&a[12];                   \
        st += KLEN;                                                   \
        if (DO_DMA) {                                                 \
            __builtin_amdgcn_sched_barrier(0);                        \
            DMA_ROW(BUFC, np, ni)                                     \
            np += KLEN; ni += KLEN;                                   \
        }                                                             \
    }

__global__ __launch_bounds__(64) void alpha_kernel(float* __restrict__ PCP,
                                                   const float* __restrict__ ICP)
{
    __shared__ float ring[8][2][1024];   // 64 KB: [buf][pcp/icp][permuted k]

    const int z = blockIdx.x;
    float* base = PCP + (size_t)z * QLEN * KLEN;
    const float* ibase = ICP + (size_t)z * QLEN * KLEN;
    const int lane = threadIdx.x;
    const int col = lane * 16;
    const int l4 = lane * 4;

    // prologue: DMA rows 0..7
    {
        const float* pp = base + col;
        const float* ip = ibase + col;
        DMA_ROW(0, pp, ip) pp += KLEN; ip += KLEN;
        DMA_ROW(1, pp, ip) pp += KLEN; ip += KLEN;
        DMA_ROW(2, pp, ip) pp += KLEN; ip += KLEN;
        DMA_ROW(3, pp, ip) pp += KLEN; ip += KLEN;
        DMA_ROW(4, pp, ip) pp += KLEN; ip += KLEN;
        DMA_ROW(5, pp, ip) pp += KLEN; ip += KLEN;
        DMA_ROW(6, pp, ip) pp += KLEN; ip += KLEN;
        DMA_ROW(7, pp, ip)
    }

    f32x4 pA0, pA1, pA2, pA3, iA0, iA1, iA2, iA3;
    f32x4 pB0, pB1, pB2, pB3, iB0, iB1, iB2, iB3;

    vwait<56>();                 // 64 outstanding -> <=56 => row 0 landed
    READ_ROW(0, A)

    float a[16];
#pragma unroll
    for (int j = 0; j < 16; ++j) a[j] = 0.0f;
    if (lane == 0) a[0] = 1.0f;

    float* st = base + col;
    const float* np = base + (size_t)8 * KLEN + col;
    const float* ni = ibase + (size_t)8 * KLEN + col;

    // steady: q = 0..503 (63 iters x 8). At step q entry: outstanding DMA
    // loads = rows q+1..q+7 = 56 (+stores); vmcnt(48) => row q+1 landed.
    for (int it = 0; it < 63; ++it) {
        STEP(48, 0, 1, true, true, A, B)
        STEP(48, 1, 2, true, true, B, A)
        STEP(48, 2, 3, true, true, A, B)
        STEP(48, 3, 4, true, true, B, A)
        STEP(48, 4, 5, true, true, A, B)
        STEP(48, 5, 6, true, true, B, A)
        STEP(48, 6, 7, true, true, A, B)
        STEP(48, 7, 0, true, true, B, A)
    }

    // drain: q = 504..511 (no more DMA; decreasing load counts)
    STEP(48, 0, 1, true, false, A, B)      // q=504
    STEP(40, 1, 2, true, false, B, A)      // q=505
    STEP(32, 2, 3, true, false, A, B)      // q=506
    STEP(24, 3, 4, true, false, B, A)      // q=507
    STEP(16, 4, 5, true, false, A, B)      // q=508
    STEP(8,  5, 6, true, false, B, A)      // q=509
    STEP(0,  6, 7, true, false, A, B)      // q=510: read row 511
    STEP(0,  7, 0, false, false, B, A)     // q=511: compute only
}

// beta[b,hca,q,k] = se * movsum_fwd3(alpha[b,hma,q,:]/den[b,hca,q,:]) for fixed hma
__global__ __launch_bounds__(256) void beta_kernel(
    const float* __restrict__ ALPHA, const float* __restrict__ SE,
    const float* __restrict__ DEN, float* __restrict__ BETA, int hma)
{
    const int rowi = blockIdx.x;
    const int q  = rowi & (QLEN - 1);
    const int bh = rowi >> 9;
    const int hca = bh & (H_CA - 1);
    const int b  = bh >> 1;

    const float* arow = ALPHA + ((((size_t)b * H_MA + hma) * QLEN + q) * KLEN);
    const float* srow = SE  + (size_t)rowi * KLEN;
    const float* drow = DEN + (size_t)rowi * KLEN;
    float* brow = BETA + (size_t)rowi * KLEN;

    __shared__ float ad[KLEN + CHUNK - 1];
    const int tid = threadIdx.x;
    const float4 a4 = *(const float4*)(arow + tid * 4);
    const float4 d4 = *(const float4*)(drow + tid * 4);
    const float ar[4] = {a4.x, a4.y, a4.z, a4.w};
    const float dr[4] = {d4.x, d4.y, d4.z, d4.w};
#pragma unroll
    for (int j = 0; j < 4; ++j)
        ad[tid * 4 + j] = ar[j] / dr[j];
    if (tid < CHUNK - 1) ad[KLEN + tid] = 0.0f;
    __syncthreads();

    const float4 s4 = *(const float4*)(srow + tid * 4);
    const float sr[4] = {s4.x, s4.y, s4.z, s4.w};
    float4 o;
    float* op = (float*)&o;
#pragma unroll
    for (int j = 0; j < 4; ++j) {
        const int k = tid * 4 + j;
        op[j] = sr[j] * (ad[k] + ad[k + 1] + ad[k + 2] + ad[k + 3]);
    }
    *(float4*)(brow + tid * 4) = o;
}

__global__ __launch_bounds__(256) void cv_gemm_kernel(
    const float* __restrict__ BETA, const float* __restrict__ VP,
    float* __restrict__ CV, int hma)
{
    const int z = blockIdx.y;
    const int b = z / H_CA;
    const int hca = z - b * H_CA;
    const int h = hma * H_CA + hca;
    const float* A  = BETA + (size_t)z * QLEN * KLEN;
    const float* Bm = VP + (size_t)b * KLEN * DIM + h * 64;
    float* C = CV + (size_t)b * QLEN * DIM + h * 64;
    gemm_nn_tile(A, KLEN, Bm, DIM, C, DIM, KLEN, nullptr, blockIdx.x * 64, 0);
}

// ---------------------------------------------------------------------------

extern "C" void kernel_launch(void* const* d_in, const int* in_sizes, int n_in,
                              void* d_out, int out_size, void* d_ws, size_t ws_size,
                              hipStream_t stream)
{
    (void)in_sizes; (void)n_in; (void)out_size; (void)ws_size;
    const float* key_t = (const float*)d_in[0];
    const float* query = (const float*)d_in[1];
    const float* wk_ma = (const float*)d_in[2];
    const float* bk_ma = (const float*)d_in[3];
    const float* wq_ma = (const float*)d_in[4];
    const float* bq_ma = (const float*)d_in[5];
    const float* r     = (const float*)d_in[6];
    const float* wk_ca = (const float*)d_in[7];
    const float* bk_ca = (const float*)d_in[8];
    const float* wq_ca = (const float*)d_in[9];
    const float* bq_ca = (const float*)d_in[10];
    const float* wv    = (const float*)d_in[11];
    const float* bv    = (const float*)d_in[12];
    const float* wo    = (const float*)d_in[13];
    const float* bo    = (const float*)d_in[14];
    float* out = (float*)d_out;

    float* ws = (float*)d_ws;
    size_t off = 0;
    float* KP_MA = ws + off; off += (size_t)B_ * KLEN * DIM;
    float* QP_MA = ws + off; off += (size_t)B_ * QLEN * DIM;
    float* KP_CA = ws + off; off += (size_t)B_ * KLEN * DIM;
    float* QP_CA = ws + off; off += (size_t)B_ * QLEN * DIM;
    float* VP    = ws + off; off += (size_t)B_ * KLEN * DIM;
    float* PCP   = ws + off; off += (size_t)B_ * H_MA * QLEN * KLEN;
    float* ICP   = ws + off; off += (size_t)B_ * H_MA * QLEN * KLEN;
    float* SE    = ws + off; off += (size_t)B_ * H_CA * QLEN * KLEN;
    float* DEN   = ws + off; off += (size_t)B_ * H_CA * QLEN * KLEN;
    float* BETA  = ws + off; off += (size_t)B_ * H_CA * QLEN * KLEN;
    float* CV    = ws + off; off += (size_t)B_ * QLEN * DIM;

    const dim3 blk(256);

    gemm_nn_kernel<<<dim3(B_ * KLEN / 64, DIM / 64), blk, 0, stream>>>(key_t, DIM, wk_ma, DIM, KP_MA, DIM, DIM, bk_ma);
    gemm_nn_kernel<<<dim3(B_ * QLEN / 64, DIM / 64), blk, 0, stream>>>(query, DIM, wq_ma, DIM, QP_MA, DIM, DIM, bq_ma);
    gemm_nn_kernel<<<dim3(B_ * KLEN / 64, DIM / 64), blk, 0, stream>>>(key_t, DIM, wk_ca, DIM, KP_CA, DIM, DIM, bk_ca);
    gemm_nn_kernel<<<dim3(B_ * QLEN / 64, DIM / 64), blk, 0, stream>>>(query, DIM, wq_ca, DIM, QP_CA, DIM, DIM, bq_ca);
    gemm_nn_kernel<<<dim3(B_ * KLEN / 64, DIM / 64), blk, 0, stream>>>(key_t, DIM, wv, DIM, VP, DIM, DIM, bv);

    energy_nt_kernel<<<dim3(QLEN / 64, KLEN / 64, B_ * H_MA), blk, 0, stream>>>(QP_MA, KP_MA, PCP, H_MA, DIM / H_MA, r);
    energy_nt_kernel<<<dim3(QLEN / 64, KLEN / 64, B_ * H_CA), blk, 0, stream>>>(QP_CA, KP_CA, SE, H_CA, DIM / H_CA, nullptr);

    ma_row_kernel<<<dim3(B_ * H_MA * QLEN), blk, 0, stream>>>(PCP, ICP);
    ca_row_kernel<<<dim3(B_ * H_CA * QLEN), blk, 0, stream>>>(SE, DEN);

    alpha_kernel<<<dim3(B_ * H_MA), dim3(64), 0, stream>>>(PCP, ICP);

    for (int hma = 0; hma < H_MA; ++hma) {
        beta_kernel<<<dim3(B_ * H_CA * QLEN), blk, 0, stream>>>(PCP, SE, DEN, BETA, hma);
        cv_gemm_kernel<<<dim3(QLEN / 64, B_ * H_CA), blk, 0, stream>>>(BETA, VP, CV, hma);
    }

    gemm_nn_kernel<<<dim3(B_ * QLEN / 64, DIM / 64), blk, 0, stream>>>(CV, DIM, wo, DIM, out, DIM, DIM, bo);
}